// Round 6
// baseline (3704.467 us; speedup 1.0000x reference)
//
#include <hip/hip_runtime.h>
#include <cstdint>

// LSTM fused kernel for MI355X — round 8: MFMA recurrence, small-ws edition.
// 16 blocks x 512 threads, MB=4 batches per block. Per step: 16x1024x256 int8
// MFMA h-GEMV (batch b duplicated into C rows 4b..4b+3 so reg=0 is the only
// live accumulator row -> 2 nonlin units/thread, compile-time), x-contribution
// via in-kernel f16 MFMA (K=32=I) accumulating into the same C registers, and
// fc(t-1) via f16 MFMA on waves 0-1 from the LDS f16 h buffer. h double-
// buffered in LDS (int8 + f16); raw s_barrier + lgkmcnt-only drains (global
// stores fly free). Workspace: 8.4 MB (< proven 51.2 MB floor). No fallback.

#define B_  64
#define T_  2048
#define I_  32
#define H_  256
#define O_  32
#define MB  4
#define NBLK 16

typedef int v4i __attribute__((ext_vector_type(4)));
typedef unsigned int v4u __attribute__((ext_vector_type(4)));
typedef float f32x4 __attribute__((ext_vector_type(4)));
typedef _Float16 f16x8 __attribute__((ext_vector_type(8)));
typedef _Float16 h2_t __attribute__((ext_vector_type(2)));

union U16x8 { v4u u; f16x8 h; };

// max over each 16-lane DPP row via row_shr; lane (16k+15) holds row max.
__device__ __forceinline__ float row16_max(float v) {
    int t;
    t = __builtin_amdgcn_update_dpp(__float_as_int(v), __float_as_int(v), 0x111, 0xf, 0xf, false);
    v = fmaxf(v, __int_as_float(t));
    t = __builtin_amdgcn_update_dpp(__float_as_int(v), __float_as_int(v), 0x112, 0xf, 0xf, false);
    v = fmaxf(v, __int_as_float(t));
    t = __builtin_amdgcn_update_dpp(__float_as_int(v), __float_as_int(v), 0x114, 0xf, 0xf, false);
    v = fmaxf(v, __int_as_float(t));
    t = __builtin_amdgcn_update_dpp(__float_as_int(v), __float_as_int(v), 0x118, 0xf, 0xf, false);
    v = fmaxf(v, __int_as_float(t));
    return v;
}

// ---------------- ws layout (8.4 MB total) ----------------
// wq2   : int8 Whh B-frags, dword idx ((c>>4)*16 + kt*4+lq)*64 + (c&15)*4 + e
// s1p   : f32 per-col Whh scale (c-order)
// biasp : f32 per-col bias (c-order)
// wihh2 : f16 Wih B-frags, dword idx ((c>>4)*4 + lq)*64 + (c&15)*4 + e
// fcf   : f16 fcw A-frags, dword idx ((fw*8+ks)*64 + l)*4 + e
// xh    : f16 x [B][T][32]
#define WQ_OFF    0
#define S1P_OFF   262144
#define BIASP_OFF 266240
#define WIHH2_OFF 270336
#define FCF_OFF   335872
#define XH_OFF    352256
// end: 8740864 bytes

__device__ __forceinline__ uint32_t pack_q(int q0, int q1, int q2, int q3) {
    return  ((uint32_t)(uint8_t)(int8_t)q0)
          | (((uint32_t)(uint8_t)(int8_t)q1) << 8)
          | (((uint32_t)(uint8_t)(int8_t)q2) << 16)
          | (((uint32_t)(uint8_t)(int8_t)q3) << 24);
}

__device__ __forceinline__ int clamp127(int v) {
    return v < -127 ? -127 : (v > 127 ? 127 : v);
}

// c-permutation: col c for gate-row (g, r):  c = ((r>>4)<<6) | (g<<4) | (r&15)
// so for wave wv, tile nt, lane lo: c = wv*128+nt*16+lo -> g = nt&3,
// r = wv*32 + (nt>>2)*16 + lo.

// -------- prep: Whh -> int8 B-frags (per-gate-row scale), Wih -> f16 B-frags --------
__global__ __launch_bounds__(64) void prep_wq(
    const float* __restrict__ Whh, const float* __restrict__ Wih,
    const float* __restrict__ bih, const float* __restrict__ bhh,
    uint32_t* __restrict__ wq2, float* __restrict__ s1p,
    float* __restrict__ biasp, uint32_t* __restrict__ wihh2)
{
    const int gr = blockIdx.x;          // gate-row 0..1023
    const int j  = threadIdx.x;         // k-dword 0..63
    const int g  = gr >> 8, r = gr & 255;
    const int c  = ((r >> 4) << 6) | (g << 4) | (r & 15);

    const float4 wv = ((const float4*)(Whh + gr * H_))[j];
    float m = fmaxf(fmaxf(fabsf(wv.x), fabsf(wv.y)), fmaxf(fabsf(wv.z), fabsf(wv.w)));
    #pragma unroll
    for (int s = 1; s < 64; s <<= 1) m = fmaxf(m, __shfl_xor(m, s, 64));
    const float S1 = fmaxf(m, 1e-20f) / 127.f;
    const float r1 = 1.f / S1;

    wq2[((c >> 4) * 16 + (j >> 2)) * 64 + (c & 15) * 4 + (j & 3)] = pack_q(
        clamp127((int)rintf(wv.x * r1)), clamp127((int)rintf(wv.y * r1)),
        clamp127((int)rintf(wv.z * r1)), clamp127((int)rintf(wv.w * r1)));

    if (j < 16) {   // Wih f16 pair dword: k = 2j, 2j+1
        union { uint32_t u; h2_t h; } z;
        z.h[0] = (_Float16)Wih[gr * I_ + 2 * j];
        z.h[1] = (_Float16)Wih[gr * I_ + 2 * j + 1];
        wihh2[((c >> 4) * 4 + (j >> 2)) * 64 + (c & 15) * 4 + (j & 3)] = z.u;
    }
    if (j == 0) { s1p[c] = S1; biasp[c] = bih[gr] + bhh[gr]; }
}

// -------- prep: x f32 -> f16 pairs --------
__global__ __launch_bounds__(256) void prep_xh(
    const float* __restrict__ x, uint32_t* __restrict__ xh)
{
    const int i = blockIdx.x * 256 + threadIdx.x;   // dword index < B*T*16
    const float2 v = ((const float2*)x)[i];
    union { uint32_t u; h2_t h; } z;
    z.h[0] = (_Float16)v.x; z.h[1] = (_Float16)v.y;
    xh[i] = z.u;
}

// -------- prep: fcw f32 -> f16 A-frags --------
__global__ __launch_bounds__(64) void prep_fcf(
    const float* __restrict__ fcw, uint32_t* __restrict__ fcf)
{
    const int id = blockIdx.x * 64 + threadIdx.x;   // 0..1023
    const int fw = id >> 9, rem = id & 511;
    const int ks = rem >> 6, l = rem & 63;
    const int o  = fw * 16 + (l & 15);
    const int kb = ks * 32 + (l >> 4) * 8;
    const float* src = fcw + o * H_ + kb;
    #pragma unroll
    for (int e = 0; e < 4; e++) {
        union { uint32_t u; h2_t h; } z;
        z.h[0] = (_Float16)src[2 * e];
        z.h[1] = (_Float16)src[2 * e + 1];
        fcf[id * 4 + e] = z.u;
    }
}

// -------- main: 16 blocks x 512 threads, MFMA recurrence --------
__global__ __launch_bounds__(512, 2) void lstm_mfma(
    const uint32_t* __restrict__ wq2, const float* __restrict__ s1p,
    const float* __restrict__ biasp, const uint32_t* __restrict__ wihh2,
    const uint32_t* __restrict__ xh, const uint32_t* __restrict__ fcf,
    const float* __restrict__ fcb, float* __restrict__ out)
{
    const int blk = blockIdx.x, tid = threadIdx.x;
    const int wvi = tid >> 6, l = tid & 63, lq = l >> 4, lo = l & 15;
    const int b   = lo >> 2;            // A-side batch (rows duplicated x4)

    __shared__ __align__(16) char     Ab[2][1088];   // int8 h, row stride 272
    __shared__ __align__(16) _Float16 hf[2][1088];   // f16 h,  row stride 272
    __shared__ int shmax[2][4];                      // per-batch |h| max

    // resident Whh int8 B-frags + per-col scale/bias
    v4i  wB[8][4];
    float s1c[8], biasc[8];
    #pragma unroll
    for (int nt = 0; nt < 8; nt++) {
        const int c = wvi * 128 + nt * 16 + lo;
        s1c[nt] = s1p[c]; biasc[nt] = biasp[c];
        #pragma unroll
        for (int kt = 0; kt < 4; kt++)
            wB[nt][kt] = *(const v4i*)(wq2 +
                (size_t)(((wvi * 8 + nt) * 16 + kt * 4 + lq) * 64 + lo * 4));
    }
    const f32x4 fcbv = *(const f32x4*)(fcb + (wvi & 1) * 16 + lq * 4);

    // init: zero h(-1) buffer (read buffer of t=0 is index 1) + maxes
    for (int i = tid; i < 1088; i += 512) Ab[1][i] = 0;
    if (tid < 8) ((int*)shmax)[tid] = 0;
    __syncthreads();

    const uint32_t* xrow = xh + ((size_t)(blk * MB + b) * T_) * 16 + lq * 4;
    v4u xA = *(const v4u*)xrow;          // x A-frag for t=0

    float cst0 = 0.f, cst1 = 0.f;        // c-state, units rr=0/1 (batch lq)

    for (int t = 0; t < T_; t++) {
        const int rb = (t & 1) ^ 1, cb = t & 1;

        // prev per-batch |h| max (finalized at t-1's barrier 1)
        const float spm = __int_as_float(shmax[rb][lq]);

        // A fragments (broadcast reads: 4 lanes share each address)
        const v4i af0 = *(const v4i*)&Ab[rb][b * 272 +   0 + lq * 16];
        const v4i af1 = *(const v4i*)&Ab[rb][b * 272 +  64 + lq * 16];
        const v4i af2 = *(const v4i*)&Ab[rb][b * 272 + 128 + lq * 16];
        const v4i af3 = *(const v4i*)&Ab[rb][b * 272 + 192 + lq * 16];

        // issue next-step x prefetch + Wih B-frag loads (L2-hot)
        const int tn = (t + 1 < T_) ? (t + 1) : t;
        const v4u xAn = *(const v4u*)(xrow + (size_t)tn * 16);
        v4u wX[8];
        #pragma unroll
        for (int nt = 0; nt < 8; nt++)
            wX[nt] = *(const v4u*)(wihh2 +
                (size_t)(((wvi * 8 + nt) * 4 + lq) * 64 + lo * 4));

        // h-GEMV: int8 MFMA, K=256 in 4 chunks
        v4i Ci[8];
        #pragma unroll
        for (int nt = 0; nt < 8; nt++) {
            v4i acc = {0, 0, 0, 0};
            acc = __builtin_amdgcn_mfma_i32_16x16x64_i8(af0, wB[nt][0], acc, 0, 0, 0);
            acc = __builtin_amdgcn_mfma_i32_16x16x64_i8(af1, wB[nt][1], acc, 0, 0, 0);
            acc = __builtin_amdgcn_mfma_i32_16x16x64_i8(af2, wB[nt][2], acc, 0, 0, 0);
            acc = __builtin_amdgcn_mfma_i32_16x16x64_i8(af3, wB[nt][3], acc, 0, 0, 0);
            Ci[nt] = acc;
        }

        // fc(t-1): waves 0-1, f16 MFMA over hf[rb]; fire-and-forget store
        if (wvi < 2 && t > 0) {
            f32x4 cfc = {0.f, 0.f, 0.f, 0.f};
            #pragma unroll
            for (int ks = 0; ks < 8; ks++) {
                U16x8 aw, bh;
                aw.u = *(const v4u*)(fcf + (size_t)(((wvi * 8 + ks) * 64 + l) * 4));
                bh.u = *(const v4u*)&hf[rb][b * 272 + ks * 32 + lq * 8];
                cfc = __builtin_amdgcn_mfma_f32_16x16x32_f16(aw.h, bh.h, cfc, 0, 0, 0);
            }
            if ((lo & 3) == 0) {
                const f32x4 r = cfc + fcbv;
                *(f32x4*)(out + ((size_t)(blk * MB + b) * T_ + (t - 1)) * O_
                          + (wvi * 16 + lq * 4)) = r;
            }
        }

        // epilogue: dequant h-term + bias into C, then x-MFMA accumulates on top
        const float sp = spm * (1.f / 127.f);
        float ga[8];
        {
            U16x8 xa; xa.u = xA;
            #pragma unroll
            for (int nt = 0; nt < 8; nt++) {
                const float v = (float)Ci[nt][0] * (s1c[nt] * sp) + biasc[nt];
                f32x4 cf = {v, v, v, v};
                U16x8 wx; wx.u = wX[nt];
                cf = __builtin_amdgcn_mfma_f32_16x16x32_f16(xa.h, wx.h, cf, 0, 0, 0);
                ga[nt] = cf[0];
            }
        }

        // nonlinearity: 2 units (batch lq; rows wvi*32+lo, wvi*32+16+lo)
        const float i0 = 1.f / (1.f + __expf(-ga[0]));
        const float f0 = 1.f / (1.f + __expf(-ga[1]));
        const float g0 = 2.f / (1.f + __expf(-2.f * ga[2])) - 1.f;
        const float o0 = 1.f / (1.f + __expf(-ga[3]));
        cst0 = f0 * cst0 + i0 * g0;
        const float h0 = o0 * (2.f / (1.f + __expf(-2.f * cst0)) - 1.f);

        const float i1 = 1.f / (1.f + __expf(-ga[4]));
        const float f1 = 1.f / (1.f + __expf(-ga[5]));
        const float g1 = 2.f / (1.f + __expf(-2.f * ga[6])) - 1.f;
        const float o1 = 1.f / (1.f + __expf(-ga[7]));
        cst1 = f1 * cst1 + i1 * g1;
        const float h1 = o1 * (2.f / (1.f + __expf(-2.f * cst1)) - 1.f);

        // per-batch max -> LDS
        float vm = fmaxf(fabsf(h0), fabsf(h1));
        vm = row16_max(vm);
        if (lo == 15) atomicMax(&shmax[cb][lq], __float_as_int(vm));

        asm volatile("s_waitcnt lgkmcnt(0)" ::: "memory");
        __builtin_amdgcn_s_barrier();                         // B1: maxes final

        const float mm = fmaxf(__int_as_float(shmax[cb][lq]), 1e-12f);
        const float rq = 127.f / mm;
        const int r0 = wvi * 32 + lo, r1 = r0 + 16;
        Ab[cb][lq * 272 + r0] = (char)(int8_t)clamp127((int)rintf(h0 * rq));
        Ab[cb][lq * 272 + r1] = (char)(int8_t)clamp127((int)rintf(h1 * rq));
        hf[cb][lq * 272 + r0] = (_Float16)h0;
        hf[cb][lq * 272 + r1] = (_Float16)h1;
        if (tid < 4) shmax[rb][tid] = 0;                      // recycle for t+1

        asm volatile("s_waitcnt lgkmcnt(0)" ::: "memory");
        __builtin_amdgcn_s_barrier();                         // B2: h(t) published

        xA = xAn;
    }

    // epilogue: fc for t = T-1
    {
        const int rbF = (T_ - 1) & 1;
        if (wvi < 2) {
            f32x4 cfc = {0.f, 0.f, 0.f, 0.f};
            #pragma unroll
            for (int ks = 0; ks < 8; ks++) {
                U16x8 aw, bh;
                aw.u = *(const v4u*)(fcf + (size_t)(((wvi * 8 + ks) * 64 + l) * 4));
                bh.u = *(const v4u*)&hf[rbF][b * 272 + ks * 32 + lq * 8];
                cfc = __builtin_amdgcn_mfma_f32_16x16x32_f16(aw.h, bh.h, cfc, 0, 0, 0);
            }
            if ((lo & 3) == 0) {
                const f32x4 r = cfc + fcbv;
                *(f32x4*)(out + ((size_t)(blk * MB + b) * T_ + (T_ - 1)) * O_
                          + (wvi * 16 + lq * 4)) = r;
            }
        }
    }
}

// ======================= launch =======================
extern "C" void kernel_launch(void* const* d_in, const int* in_sizes, int n_in,
                              void* d_out, int out_size, void* d_ws, size_t ws_size,
                              hipStream_t stream) {
    const float* x    = (const float*)d_in[0];
    const float* Wih  = (const float*)d_in[1];
    const float* Whh  = (const float*)d_in[2];
    const float* bih  = (const float*)d_in[3];
    const float* bhh  = (const float*)d_in[4];
    const float* fcw  = (const float*)d_in[5];
    const float* fcb  = (const float*)d_in[6];
    float* out = (float*)d_out;

    char* ws = (char*)d_ws;
    uint32_t* wq2   = (uint32_t*)(ws + WQ_OFF);
    float*    s1p   = (float*)(ws + S1P_OFF);
    float*    biasp = (float*)(ws + BIASP_OFF);
    uint32_t* wihh2 = (uint32_t*)(ws + WIHH2_OFF);
    uint32_t* fcf   = (uint32_t*)(ws + FCF_OFF);
    uint32_t* xh    = (uint32_t*)(ws + XH_OFF);

    prep_wq<<<1024, 64, 0, stream>>>(Whh, Wih, bih, bhh, wq2, s1p, biasp, wihh2);
    prep_xh<<<(B_ * T_ * 16) / 256, 256, 0, stream>>>(x, xh);
    prep_fcf<<<16, 64, 0, stream>>>(fcw, fcf);
    lstm_mfma<<<NBLK, 512, 0, stream>>>(wq2, s1p, biasp, wihh2, xh, fcf, fcb, out);
}